// Round 10
// baseline (237.318 us; speedup 1.0000x reference)
//
#include <hip/hip_runtime.h>

constexpr int Tt = 384;   // timesteps
constexpr int Cc = 96;    // classes (blank = 95)
constexpr int Ll = 48;    // max label length
constexpr int Gg = 8;     // rows per group (= rescale period)
constexpr int NG = 24;    // groups per half (24*8 = 192)

#define L2E 1.4426950408889634f
#define LN2 0.6931471805599453f
#define LNEG (-3.0e38f)

// ---- DPP helpers (VALU pipe) ----
template <int CTRL, int RM = 0xF>
__device__ __forceinline__ float dppf(float x) {
    return __int_as_float(
        __builtin_amdgcn_update_dpp(0, __float_as_int(x), CTRL, RM, 0xF, true));
}
template <int CTRL>
__device__ __forceinline__ int dppi(int x) {
    return __builtin_amdgcn_update_dpp(0, x, CTRL, 0xF, 0xF, true);
}
__device__ __forceinline__ float bcast63(float x) {
    return __int_as_float(__builtin_amdgcn_readlane(__float_as_int(x), 63));
}
// full-wave sum of non-negative values, result broadcast
__device__ __forceinline__ float wsum(float x) {
    x += dppf<0x111>(x);          // row_shr:1
    x += dppf<0x112>(x);          // row_shr:2
    x += dppf<0x114>(x);          // row_shr:4
    x += dppf<0x118>(x);          // row_shr:8
    x += dppf<0x142, 0xA>(x);     // row_bcast:15 -> rows 1,3
    x += dppf<0x143, 0xC>(x);     // row_bcast:31 -> rows 2,3
    return bcast63(x);
}
__device__ __forceinline__ float shup1(float x) { return dppf<0x138>(x); } // lane i <- i-1, 0 into lane 0
__device__ __forceinline__ float shdn1(float x) { return dppf<0x130>(x); } // lane i <- i+1, 0 into lane 63
__device__ __forceinline__ float exp2i(int d) {  // 2^d, clamped to fp32-normal range
    d = d < -126 ? -126 : (d > 126 ? 126 : d);
    return __int_as_float((d + 127) << 23);
}

// ---- DP gather loads for one 8-row group (R6-verified pattern) ----
// lane i reads raw logits logit[t][label_i] and logit[t][95] (uniform -> broadcast).
template <bool FWD>
__device__ __forceinline__ void dp_load(const float* __restrict__ rp, float* ql,
                                        float* qb, int g, int labv) {
#pragma unroll
    for (int j = 0; j < Gg; ++j) {
        int k = g * Gg + j;
        int t = FWD ? k : (Tt - 1 - k);
        ql[j] = rp[t * Cc + labv];
        qb[j] = rp[t * Cc + 95];
    }
}

// ---- one 8-step DP group on UNNORMALIZED emissions (R6/R9-verified) ----
template <bool FWD>
__device__ __forceinline__ void dp_group(const float* ql, const float* qb,
                                         float allow2f, float& st_e, float& st_o,
                                         int& ls, float& f, float& a2f) {
    float el[Gg], eb[Gg];
#pragma unroll
    for (int j = 0; j < Gg; ++j) {
        el[j] = __builtin_amdgcn_exp2f(ql[j] * L2E);
        eb[j] = __builtin_amdgcn_exp2f(qb[j] * L2E);
    }
#pragma unroll
    for (int j = 0; j < Gg; ++j) {
        if (FWD) {
            float sh = shup1(st_o);                      // alpha(2i-1), lane i-1 scale
            float t0 = st_e + st_o;
            float ne = fmaf(f, sh, st_e) * eb[j];
            float no = fmaf(a2f, sh, t0) * el[j];
            st_e = ne; st_o = no;
        } else {
            float en = shdn1(st_e);                      // beta(2i+2)
            float on = shdn1(st_o);                      // beta(2i+3)
            float ne = (st_e + st_o) * eb[j];
            float no = fmaf(a2f, on, fmaf(f, en, st_o)) * el[j];
            st_e = ne; st_o = no;
        }
    }
    // per-lane exact power-of-2 rescale (absorbs unnormalized dynamic range;
    // Z_t is lane-common so inter-lane exponent differences are unchanged)
    float m = fmaxf(st_e, st_o);
    bool z  = (m == 0.0f);
    int eb2 = (__float_as_int(m) >> 23) & 0xFF;
    eb2 = eb2 > 253 ? 253 : eb2;
    float r = z ? 1.0f : __int_as_float((254 - eb2) << 23);   // 2^(127-eb2), exact
    st_e *= r; st_o *= r;
    ls += z ? 0 : (eb2 - 127);
    // exponent adoption for zero lanes (front moves <= 8 lanes/group)
#pragma unroll
    for (int it = 0; it < 8; ++it) {
        int lsn = FWD ? dppi<0x138>(ls) : dppi<0x130>(ls);
        ls = z ? lsn : ls;
    }
    int lsn2 = FWD ? dppi<0x138>(ls) : dppi<0x130>(ls);
    f   = exp2i(lsn2 - ls);
    a2f = allow2f * f;
}

// ---- DP half: A/B double-buffer, load 2 groups ahead, no barriers ----
template <bool FWD>
__device__ __forceinline__ void run_half(const float* __restrict__ rp, int labv,
                                         float allow2f, float& st_e, float& st_o,
                                         int& ls, float& f, float& a2f) {
    float qlA[Gg], qbA[Gg], qlB[Gg], qbB[Gg];
    dp_load<FWD>(rp, qlA, qbA, 0, labv);
    dp_load<FWD>(rp, qlB, qbB, 1, labv);
    for (int g2 = 0; g2 < NG / 2; ++g2) {
        bool more = (g2 < NG / 2 - 1);
        dp_group<FWD>(qlA, qbA, allow2f, st_e, st_o, ls, f, a2f);   // group 2*g2
        if (more) dp_load<FWD>(rp, qlA, qbA, 2 * g2 + 2, labv);     // in flight over B
        dp_group<FWD>(qlB, qbB, allow2f, st_e, st_o, ls, f, a2f);   // group 2*g2+1
        if (more) dp_load<FWD>(rp, qlB, qbB, 2 * g2 + 3, labv);
    }
}

// 8 waves/block, 1 element/block, fully decoupled roles, ONE barrier at the end:
//   wv0 = fwd DP (t=0..191), wv1 = bwd DP (t=383..192)  [gather-DP, unnormalized]
//   wv2..7 = zsum: wave w streams rows [64(w-2), 64(w-2)+64), f64 partial of log2 Z
__global__ __launch_bounds__(512, 8) void ctc_fb(const int* __restrict__ labels,
                                                 const float* __restrict__ pred,
                                                 float* __restrict__ nll) {
    const int b    = blockIdx.x;
    const int lane = threadIdx.x & 63;
    const int wv   = threadIdx.x >> 6;
    const float* rp = pred + (size_t)b * Tt * Cc;

    __shared__ float  sbe[64], sbo[64];
    __shared__ int    slsb[64];
    __shared__ double part[6];

    float st_e = 0.0f, st_o = 0.0f, f = 1.0f, a2f = 0.0f, allow2f = 0.0f;
    int   ls = 0;
    int   labv = 0, len = 0;

    if (wv < 2) {
        // ---------------- DP waves ----------------
        int v = (lane < Ll) ? labels[(size_t)b * Ll + lane] : -1;
        int present = (lane < Ll) && (v != -1);
        labv = (v < 0) ? 0 : v;
        unsigned long long pm = __ballot(present);
        len = __popcll(pm);
        int lab_p = __shfl(labv, (lane - 1) & 63, 64);
        int lab_n = __shfl(labv, (lane + 1) & 63, 64);
        if (wv == 0) {        // fwd: virtual pre-start state at lane 0
            allow2f = (lane >= 1 && labv != lab_p) ? 1.0f : 0.0f;
            st_e = (lane == 0) ? 1.0f : 0.0f;
            a2f = allow2f;
            run_half<true>(rp, labv, allow2f, st_e, st_o, ls, f, a2f);
        } else {              // bwd: virtual post-end state at lane == len
            allow2f = (labv != lab_n) ? 1.0f : 0.0f;
            st_e = (lane == len) ? 1.0f : 0.0f;
            a2f = allow2f;
            run_half<false>(rp, labv, allow2f, st_e, st_o, ls, f, a2f);
            sbe[lane]  = st_e;
            sbo[lane]  = st_o;
            slsb[lane] = ls;
        }
    } else {
        // ---------------- zsum waves (R6-verified arithmetic) ----------------
        const float2* rp2 = (const float2*)rp;
        const int t0 = (wv - 2) * 64;
        double acc = 0.0;
        float2 qa = (lane < 48) ? rp2[(size_t)t0 * 48 + lane] : make_float2(-1e4f, -1e4f);
        for (int j = 0; j < 64; ++j) {
            float2 qn = qa;
            if (j + 1 < 64)
                qn = (lane < 48) ? rp2[(size_t)(t0 + j + 1) * 48 + lane]
                                 : make_float2(-1e4f, -1e4f);
            float ex = __builtin_amdgcn_exp2f(qa.x * L2E);   // lanes>=48 -> 0
            float ey = __builtin_amdgcn_exp2f(qa.y * L2E);
            float z  = wsum(ex + ey);
            acc += (double)__log2f(z);
            qa = qn;
        }
        if (lane == 0) part[wv - 2] = acc;
    }
    __syncthreads();   // the ONLY inter-wave sync

    if (wv == 0) {
        // transition half-step (no emission) to meet beta at t = 192
        float sh  = shup1(st_o);
        int   lsu = dppi<0x138>(ls);
        float fup = exp2i(lsu - ls);
        float Ae = fmaf(fup, sh, st_e);
        float Ao = fmaf(allow2f * fup, sh, st_e + st_o);
        // combine in log2 domain with integer exponents restored
        float be = sbe[lane], bo = sbo[lane];
        float base = (float)(ls + slsb[lane]);
        float l1 = (Ae > 0.0f && be > 0.0f) ? __log2f(Ae) + __log2f(be) + base : LNEG;
        float l2 = (Ao > 0.0f && bo > 0.0f) ? __log2f(Ao) + __log2f(bo) + base : LNEG;
        float mm = fmaxf(l1, l2);
#pragma unroll
        for (int off = 32; off >= 1; off >>= 1) mm = fmaxf(mm, __shfl_xor(mm, off, 64));
        float ss = exp2f(l1 - mm) + exp2f(l2 - mm);
#pragma unroll
        for (int off = 32; off >= 1; off >>= 1) ss += __shfl_xor(ss, off, 64);
        if (lane == 0) {
            double zt = 0.0;
#pragma unroll
            for (int w = 0; w < 6; ++w) zt += part[w];   // fixed-order f64
            float ll = (mm + __log2f(ss) - (float)zt) * LN2;
            nll[b] = -ll;                 // plain store, no contended atomic
        }
    }
}

// ---- mean of 1024 per-example NLLs, fixed-order f64, single block ----
__global__ __launch_bounds__(256) void ctc_mean(const float* __restrict__ nll,
                                                float* __restrict__ out, float invB) {
    __shared__ double part[256];
    double s = 0.0;
#pragma unroll
    for (int i = 0; i < 4; ++i) s += (double)nll[threadIdx.x + 256 * i];
    part[threadIdx.x] = s;
    __syncthreads();
#pragma unroll
    for (int w = 128; w >= 1; w >>= 1) {
        if (threadIdx.x < w) part[threadIdx.x] += part[threadIdx.x + w];
        __syncthreads();
    }
    if (threadIdx.x == 0) out[0] = (float)(part[0] * (double)invB);
}

extern "C" void kernel_launch(void* const* d_in, const int* in_sizes, int n_in,
                              void* d_out, int out_size, void* d_ws, size_t ws_size,
                              hipStream_t stream) {
    const int*   labels = (const int*)d_in[0];
    const float* pred   = (const float*)d_in[1];
    float*       out    = (float*)d_out;
    float*       nll    = (float*)d_ws;    // 1024 floats = 4 KB

    const int B = in_sizes[0] / Ll;  // 1024

    hipLaunchKernelGGL(ctc_fb, dim3(B), dim3(512), 0, stream, labels, pred, nll);
    hipLaunchKernelGGL(ctc_mean, dim3(1), dim3(256), 0, stream, nll, out, 1.0f / (float)B);
}

// Round 11
// 227.826 us; speedup vs baseline: 1.0417x; 1.0417x over previous
//
#include <hip/hip_runtime.h>

constexpr int Tt = 384;   // timesteps
constexpr int Cc = 96;    // classes (blank = 95)
constexpr int Ll = 48;    // max label length
constexpr int Gg = 8;     // rows per group (= rescale period)
constexpr int NG = 24;    // groups per half (24*8 = 192)
constexpr int RSLOTS = 6;             // LDS ring slots per wave
constexpr int SLOTB  = Gg * Cc * 4;   // 3072 B per group slot
constexpr int RINGB  = RSLOTS * SLOTB + 512;   // + tail pad for lane>=48 overreads

#define L2E 1.4426950408889634f
#define LN2 0.6931471805599453f
#define LNEG (-3.0e38f)

typedef __attribute__((address_space(3))) void       lds_t;
typedef const __attribute__((address_space(1))) void gmem_t;

// ---- DPP helpers (VALU pipe) ----
template <int CTRL, int RM = 0xF>
__device__ __forceinline__ float dppf(float x) {
    return __int_as_float(
        __builtin_amdgcn_update_dpp(0, __float_as_int(x), CTRL, RM, 0xF, true));
}
template <int CTRL>
__device__ __forceinline__ int dppi(int x) {
    return __builtin_amdgcn_update_dpp(0, x, CTRL, 0xF, 0xF, true);
}
__device__ __forceinline__ float bcast63(float x) {
    return __int_as_float(__builtin_amdgcn_readlane(__float_as_int(x), 63));
}
// full-wave sum of non-negative values, result broadcast
__device__ __forceinline__ float wsum(float x) {
    x += dppf<0x111>(x);          // row_shr:1
    x += dppf<0x112>(x);          // row_shr:2
    x += dppf<0x114>(x);          // row_shr:4
    x += dppf<0x118>(x);          // row_shr:8
    x += dppf<0x142, 0xA>(x);     // row_bcast:15 -> rows 1,3
    x += dppf<0x143, 0xC>(x);     // row_bcast:31 -> rows 2,3
    return bcast63(x);
}
__device__ __forceinline__ float shup1(float x) { return dppf<0x138>(x); } // lane i <- i-1
__device__ __forceinline__ float shdn1(float x) { return dppf<0x130>(x); } // lane i <- i+1
__device__ __forceinline__ float exp2i(int d) {  // 2^d, clamped to fp32-normal range
    d = d < -126 ? -126 : (d > 126 ? 126 : d);
    return __int_as_float((d + 127) << 23);
}

// ---- stage one 8-row group (3 KB) into a wave-private LDS slot, 3 DMA instrs ----
// global_load_lds: dst = slot_base + lane*16 (+c*1024), src per-lane. No VGPR results.
template <bool FWD>
__device__ __forceinline__ void stage_group(const float* __restrict__ rp, char* slot,
                                            int g, int lane) {
    const int t0 = FWD ? (8 * g) : (376 - 8 * g);       // lowest t in this group
    const char* src = (const char*)(rp + (size_t)t0 * Cc);
#pragma unroll
    for (int c = 0; c < 3; ++c) {
        __builtin_amdgcn_global_load_lds((gmem_t*)(src + c * 1024 + lane * 16),
                                         (lds_t*)(slot + c * 1024), 16, 0, 0);
    }
}

// ---- consume one staged group: exp2 + gathers + wsum side-chain (R9 arithmetic) ----
// el[j] = e(label_lane), eb[j] = e(blank), unnormalized; zacc += log2(Z_row).
template <bool FWD>
__device__ __forceinline__ void consume_group(const char* slot, int lane,
                                              int idx_h, int bitsel, double& zacc,
                                              float* el, float* eb) {
#pragma unroll
    for (int j = 0; j < Gg; ++j) {
        const int off = FWD ? j : (7 - j);              // k-row j at t-offset within slot
        float2 q = *(const float2*)(slot + off * 384 + lane * 8);  // lanes>=48: finite junk
        float ex = __builtin_amdgcn_exp2f(q.x * L2E);
        float ey = __builtin_amdgcn_exp2f(q.y * L2E);
        float gb = __shfl(ey, 47, 64);      // class 95 (blank)
        float g0 = __shfl(ex, idx_h, 64);   // class 2*idx_h   (idx_h < 48)
        float g1 = __shfl(ey, idx_h, 64);   // class 2*idx_h+1
        el[j] = bitsel ? g1 : g0;
        eb[j] = gb;
        float s = wsum((lane < 48) ? (ex + ey) : 0.0f); // junk lanes masked before sum
        zacc += (double)__log2f(s);         // wave-uniform side-chain
    }
}

// ---- one 8-step DP group on UNNORMALIZED emissions (R6/R9-verified) ----
template <bool FWD>
__device__ __forceinline__ void dp_group(const float* el, const float* eb,
                                         float allow2f, float& st_e, float& st_o,
                                         int& ls, float& f, float& a2f) {
#pragma unroll
    for (int j = 0; j < Gg; ++j) {
        if (FWD) {
            float sh = shup1(st_o);                      // alpha(2i-1), lane i-1 scale
            float t0 = st_e + st_o;
            float ne = fmaf(f, sh, st_e) * eb[j];
            float no = fmaf(a2f, sh, t0) * el[j];
            st_e = ne; st_o = no;
        } else {
            float en = shdn1(st_e);                      // beta(2i+2)
            float on = shdn1(st_o);                      // beta(2i+3)
            float ne = (st_e + st_o) * eb[j];
            float no = fmaf(a2f, on, fmaf(f, en, st_o)) * el[j];
            st_e = ne; st_o = no;
        }
    }
    // per-lane exact power-of-2 rescale (absorbs unnormalized dynamic range)
    float m = fmaxf(st_e, st_o);
    bool z  = (m == 0.0f);
    int eb2 = (__float_as_int(m) >> 23) & 0xFF;
    eb2 = eb2 > 253 ? 253 : eb2;
    float r = z ? 1.0f : __int_as_float((254 - eb2) << 23);   // 2^(127-eb2), exact
    st_e *= r; st_o *= r;
    ls += z ? 0 : (eb2 - 127);
    // exponent adoption for zero lanes (front moves <= 8 lanes/group)
#pragma unroll
    for (int it = 0; it < 8; ++it) {
        int lsn = FWD ? dppi<0x138>(ls) : dppi<0x130>(ls);
        ls = z ? lsn : ls;
    }
    int lsn2 = FWD ? dppi<0x138>(ls) : dppi<0x130>(ls);
    f   = exp2i(lsn2 - ls);
    a2f = allow2f * f;
}

// ---- half-problem: 6-slot LDS ring, counted vmcnt, no barriers, no coupling ----
template <bool FWD>
__device__ __forceinline__ void run_half(const float* __restrict__ rp, char* ring,
                                         int lane, int idx_h, int bitsel,
                                         float allow2f, float& st_e, float& st_o,
                                         int& ls, float& f, float& a2f, double& zacc) {
#pragma unroll
    for (int g = 0; g < RSLOTS; ++g)                    // prologue: 18 DMA loads in flight
        stage_group<FWD>(rp, ring + g * SLOTB, g, lane);
    float el[Gg], eb[Gg];
    for (int g = 0; g < NG; ++g) {
        // slot g ready when the 5 newer groups' 15 loads may remain outstanding
        asm volatile("s_waitcnt vmcnt(15)" ::: "memory");
        __builtin_amdgcn_sched_barrier(0);
        consume_group<FWD>(ring + (g % RSLOTS) * SLOTB, lane, idx_h, bitsel, zacc, el, eb);
        dp_group<FWD>(el, eb, allow2f, st_e, st_o, ls, f, a2f);
        __builtin_amdgcn_sched_barrier(0);
        asm volatile("s_waitcnt lgkmcnt(0)" ::: "memory");   // ds_reads retired pre-reuse
        if (g + RSLOTS < NG)
            stage_group<FWD>(rp, ring + (g % RSLOTS) * SLOTB, g + RSLOTS, lane);
    }
}

// 2 waves/block: wv0 = fwd half (t=0..191), wv1 = bwd half (t=383..192). No main-loop
// barriers; one barrier to combine at t=192. Per-example NLL -> ws[b] (no atomics).
__global__ __launch_bounds__(128) void ctc_fb(const int* __restrict__ labels,
                                              const float* __restrict__ pred,
                                              float* __restrict__ nll) {
    const int b    = blockIdx.x;
    const int lane = threadIdx.x & 63;
    const int wv   = threadIdx.x >> 6;
    const float* rp = pred + (size_t)b * Tt * Cc;

    __shared__ __align__(16) char ring[2][RINGB];   // ~38 KB, wave-private halves
    __shared__ float  sbe[64], sbo[64];
    __shared__ int    slsb[64];
    __shared__ double szb;

    // lane i holds label i
    int v = (lane < Ll) ? labels[(size_t)b * Ll + lane] : -1;
    int present = (lane < Ll) && (v != -1);
    int labv = (v < 0) ? 0 : v;
    unsigned long long pm = __ballot(present);
    int len = __popcll(pm);
    int idx_h  = labv >> 1;
    int bitsel = labv & 1;
    int lab_p = __shfl(labv, (lane - 1) & 63, 64);
    int lab_n = __shfl(labv, (lane + 1) & 63, 64);

    float st_e, st_o = 0.0f, f = 1.0f, a2f, allow2f;
    int   ls = 0;
    double zacc = 0.0;

    if (wv == 0) {            // fwd DP: virtual pre-start state at lane 0
        allow2f = (lane >= 1 && labv != lab_p) ? 1.0f : 0.0f;
        st_e = (lane == 0) ? 1.0f : 0.0f;
        a2f = allow2f;
        run_half<true>(rp, ring[0], lane, idx_h, bitsel, allow2f,
                       st_e, st_o, ls, f, a2f, zacc);
    } else {                  // bwd DP: virtual post-end state at lane == len
        allow2f = (labv != lab_n) ? 1.0f : 0.0f;
        st_e = (lane == len) ? 1.0f : 0.0f;
        a2f = allow2f;
        run_half<false>(rp, ring[1], lane, idx_h, bitsel, allow2f,
                        st_e, st_o, ls, f, a2f, zacc);
        sbe[lane]  = st_e;
        sbo[lane]  = st_o;
        slsb[lane] = ls;
        if (lane == 0) szb = zacc;   // wave-uniform
    }
    __syncthreads();

    if (wv == 0) {
        // transition half-step (no emission) to meet beta at t = 192
        float sh  = shup1(st_o);
        int   lsu = dppi<0x138>(ls);
        float fup = exp2i(lsu - ls);
        float Ae = fmaf(fup, sh, st_e);
        float Ao = fmaf(allow2f * fup, sh, st_e + st_o);
        // combine in log2 domain with integer exponents restored
        float be = sbe[lane], bo = sbo[lane];
        float base = (float)(ls + slsb[lane]);
        float l1 = (Ae > 0.0f && be > 0.0f) ? __log2f(Ae) + __log2f(be) + base : LNEG;
        float l2 = (Ao > 0.0f && bo > 0.0f) ? __log2f(Ao) + __log2f(bo) + base : LNEG;
        float mm = fmaxf(l1, l2);
#pragma unroll
        for (int off = 32; off >= 1; off >>= 1) mm = fmaxf(mm, __shfl_xor(mm, off, 64));
        float ss = exp2f(l1 - mm) + exp2f(l2 - mm);
#pragma unroll
        for (int off = 32; off >= 1; off >>= 1) ss += __shfl_xor(ss, off, 64);
        if (lane == 0) {
            // subtract the factored-out log2(prod_t Z_t) over both halves
            double zt = zacc + szb;
            float ll = (mm + __log2f(ss) - (float)zt) * LN2;
            nll[b] = -ll;                 // plain store, no contended atomic
        }
    }
}

// ---- mean of 1024 per-example NLLs, fixed-order f64, single block ----
__global__ __launch_bounds__(256) void ctc_mean(const float* __restrict__ nll,
                                                float* __restrict__ out, float invB) {
    __shared__ double part[256];
    double s = 0.0;
#pragma unroll
    for (int i = 0; i < 4; ++i) s += (double)nll[threadIdx.x + 256 * i];
    part[threadIdx.x] = s;
    __syncthreads();
#pragma unroll
    for (int w = 128; w >= 1; w >>= 1) {
        if (threadIdx.x < w) part[threadIdx.x] += part[threadIdx.x + w];
        __syncthreads();
    }
    if (threadIdx.x == 0) out[0] = (float)(part[0] * (double)invB);
}

extern "C" void kernel_launch(void* const* d_in, const int* in_sizes, int n_in,
                              void* d_out, int out_size, void* d_ws, size_t ws_size,
                              hipStream_t stream) {
    const int*   labels = (const int*)d_in[0];
    const float* pred   = (const float*)d_in[1];
    float*       out    = (float*)d_out;
    float*       nll    = (float*)d_ws;    // 1024 floats = 4 KB

    const int B = in_sizes[0] / Ll;  // 1024

    hipLaunchKernelGGL(ctc_fb, dim3(B), dim3(128), 0, stream, labels, pred, nll);
    hipLaunchKernelGGL(ctc_mean, dim3(1), dim3(256), 0, stream, nll, out, 1.0f / (float)B);
}